// Round 1
// baseline (338.043 us; speedup 1.0000x reference)
//
#include <hip/hip_runtime.h>
#include <hip/hip_bf16.h>
#include <stdint.h>

// Problem constants (B=4096, D=2048, K=8, H2=64)
#define NB 4096
#define ND 2048
#define NK 8
#define NH 64

// GEMM tile config (m97-style: 128x128 tile, BK=32, 16x16x32 bf16 MFMA)
#define BM 128
#define BN 128
#define BK 32
#define MAX_ROWS 5120   // 4096 + 8*128 padding worst case
#define MAX_TILES 40    // sum ceil(n_k/128) <= 39

typedef __bf16 bf16;
typedef __bf16 bf16x8 __attribute__((ext_vector_type(8)));
typedef float floatx4 __attribute__((ext_vector_type(4)));

// Workspace layout (bytes). Requires ws_size >= ~88.2 MB (the natural dense
// intermediate y1 [B, D*K] fp32 is 128 MB, so ws should be at least that).
#define OFF_KIDX   0u          // 4096 int
#define OFF_ORDER  16384u      // 5120 int (-1 = padding row)
#define OFF_META   40960u      // [0]=n_mtiles, [1..40]=tile branch, [41..80]=tile row0
#define OFF_XG     65536u      // 5120*2048 bf16 = 20971520 B
#define OFF_WB     21037056u   // 8*2048*2048 bf16 = 67108864 B -> end 88145920

// ---------------------------------------------------------------------------
// Kernel 1: single-block prep. Branch index per sample, per-branch counts,
// padded sample ordering, M-tile table, fc2-side scalar c2[k], out init.
// ---------------------------------------------------------------------------
__global__ void prep_kernel(const float* __restrict__ intention,
                            const float* __restrict__ W2,
                            const float* __restrict__ b2,
                            const float* __restrict__ W3,
                            const float* __restrict__ b3,
                            int* __restrict__ kidx,
                            int* __restrict__ order,
                            int* __restrict__ meta,
                            float* __restrict__ out)
{
    __shared__ int cnt[NK];
    __shared__ int cur[NK];
    __shared__ float c2s[NK];
    const int tid = threadIdx.x;

    if (tid < NK) cnt[tid] = 0;
    for (int i = tid; i < MAX_ROWS; i += 256) order[i] = -1;
    __syncthreads();

    // branch argmax (one-hot: the entry > 0.5)
    for (int b = tid; b < NB; b += 256) {
        const float* row = intention + b * NK;
        int k = 0;
#pragma unroll
        for (int j = 1; j < NK; j++)
            if (row[j] > 0.5f) k = j;
        kidx[b] = k;
        atomicAdd(&cnt[k], 1);
    }
    __syncthreads();

    if (tid == 0) {
        int running = 0, nt = 0;
        for (int k = 0; k < NK; k++) {
            cur[k] = running;
            int ntile = (cnt[k] + BM - 1) / BM;
            for (int t = 0; t < ntile; t++) {
                meta[1 + nt] = k;
                meta[1 + MAX_TILES + nt] = running + t * BM;
                nt++;
            }
            running += ntile * BM;
        }
        meta[0] = nt;
    }
    __syncthreads();

    // scatter sample indices grouped by branch (order within branch irrelevant)
    for (int b = tid; b < NB; b += 256) {
        int k = kidx[b];
        int pos = atomicAdd(&cur[k], 1);
        order[pos] = b;
    }

    // c2[k] = b3 + sum_h relu(W2[h,k] + b2[h]) * W3[D + h]
    if (tid < NK) {
        float s = b3[0];
        for (int h = 0; h < NH; h++) {
            float v = W2[h * NK + tid] + b2[h];
            if (v > 0.f) s += v * W3[ND + h];
        }
        c2s[tid] = s;
    }
    __syncthreads();

    for (int b = tid; b < NB; b += 256)
        out[b] = c2s[kidx[b]];
}

// ---------------------------------------------------------------------------
// Kernel 2: gather + convert x rows to bf16 into branch-grouped padded xg.
// One block per padded row; padding rows (order=-1) are zero-filled.
// ---------------------------------------------------------------------------
__global__ void gather_x_kernel(const float* __restrict__ x,
                                const int* __restrict__ order,
                                bf16* __restrict__ xg)
{
    const int row = blockIdx.x;
    const int t = threadIdx.x;
    const int b = order[row];
    bf16* dst = xg + (size_t)row * ND + t * 8;
    bf16x8 v;
    if (b < 0) {
#pragma unroll
        for (int i = 0; i < 8; i++) v[i] = (bf16)0.f;
    } else {
        const float* src = x + (size_t)b * ND + t * 8;
        float4 a = *(const float4*)(src);
        float4 c = *(const float4*)(src + 4);
        v[0] = (bf16)a.x; v[1] = (bf16)a.y; v[2] = (bf16)a.z; v[3] = (bf16)a.w;
        v[4] = (bf16)c.x; v[5] = (bf16)c.y; v[6] = (bf16)c.z; v[7] = (bf16)c.w;
    }
    *(bf16x8*)dst = v;
}

// ---------------------------------------------------------------------------
// Kernel 3: convert W1 (fp32, rows interleaved by branch: row d*8+k) into
// per-branch contiguous bf16 Wb[k][d][c]. One block per W1 row.
// ---------------------------------------------------------------------------
__global__ void conv_w1_kernel(const float* __restrict__ W1,
                               bf16* __restrict__ Wb)
{
    const int r = blockIdx.x;      // 0..16383
    const int t = threadIdx.x;
    const int d = r >> 3;
    const int k = r & 7;
    const float* src = W1 + (size_t)r * ND + t * 8;
    bf16* dst = Wb + ((size_t)k * ND + d) * ND + t * 8;
    float4 a = *(const float4*)(src);
    float4 c = *(const float4*)(src + 4);
    bf16x8 v;
    v[0] = (bf16)a.x; v[1] = (bf16)a.y; v[2] = (bf16)a.z; v[3] = (bf16)a.w;
    v[4] = (bf16)c.x; v[5] = (bf16)c.y; v[6] = (bf16)c.z; v[7] = (bf16)c.w;
    *(bf16x8*)dst = v;
}

// ---------------------------------------------------------------------------
// Kernel 4: per-branch bf16 GEMM (C = Xg . Wb_k^T), m97 structure:
// 128x128 tile, BK=32, global_load_lds width 16, 4 waves each 64x64 via
// 4x4 grid of 16x16x32 MFMA. Fused epilogue: +b1, relu, *W3, row-reduce,
// atomicAdd into out[order[row]].
// ---------------------------------------------------------------------------
__global__ void gemm_kernel(const bf16* __restrict__ xg,
                            const bf16* __restrict__ Wb,
                            const int* __restrict__ order,
                            const int* __restrict__ meta,
                            const float* __restrict__ b1,
                            const float* __restrict__ W3,
                            float* __restrict__ out)
{
    const int n_mt = meta[0];
    const int mt = blockIdx.y;
    if (mt >= n_mt) return;
    const int kbr = meta[1 + mt];
    const int row0 = meta[1 + MAX_TILES + mt];
    const int col0 = blockIdx.x * BN;

    __shared__ bf16 As[BM * BK];   // [128][32] row-major, 8 KB
    __shared__ bf16 Bs[BN * BK];   // [128][32] row-major, 8 KB

    const int tid = threadIdx.x;
    const int lane = tid & 63;
    const int wid = tid >> 6;
    const int wm = wid >> 1;       // 0..1
    const int wn = wid & 1;        // 0..1

    const bf16* Abase = xg + (size_t)row0 * ND;
    const bf16* Bbase = Wb + ((size_t)kbr * ND + col0) * ND;

    // staging: round r covers rows r*64..r*64+63; 4 threads per 64B row chunk
    const int srow = tid >> 2;            // 0..63
    const int scol = (tid & 3) * 8;       // bf16 elements

    floatx4 zero = {0.f, 0.f, 0.f, 0.f};
    floatx4 acc[4][4];
#pragma unroll
    for (int i = 0; i < 4; i++)
#pragma unroll
        for (int j = 0; j < 4; j++) acc[i][j] = zero;

    const int qk = (lane >> 4) * 8;       // k-offset within frag
    const int mrow = lane & 15;

    for (int kk = 0; kk < ND; kk += BK) {
#pragma unroll
        for (int r = 0; r < 2; r++) {
            const bf16* ga = Abase + (size_t)(r * 64 + srow) * ND + kk + scol;
            const bf16* gb = Bbase + (size_t)(r * 64 + srow) * ND + kk + scol;
            bf16* la = As + r * 2048 + wid * 512;   // wave-uniform base
            bf16* lb = Bs + r * 2048 + wid * 512;
            __builtin_amdgcn_global_load_lds(
                (const __attribute__((address_space(1))) void*)ga,
                (__attribute__((address_space(3))) void*)la, 16, 0, 0);
            __builtin_amdgcn_global_load_lds(
                (const __attribute__((address_space(1))) void*)gb,
                (__attribute__((address_space(3))) void*)lb, 16, 0, 0);
        }
        __syncthreads();

        bf16x8 af[4], bfv[4];
#pragma unroll
        for (int i = 0; i < 4; i++) {
            af[i]  = *(const bf16x8*)(As + (wm * 64 + i * 16 + mrow) * BK + qk);
            bfv[i] = *(const bf16x8*)(Bs + (wn * 64 + i * 16 + mrow) * BK + qk);
        }
#pragma unroll
        for (int i = 0; i < 4; i++)
#pragma unroll
            for (int j = 0; j < 4; j++)
                acc[i][j] = __builtin_amdgcn_mfma_f32_16x16x32_bf16(
                    af[i], bfv[j], acc[i][j], 0, 0, 0);
        __syncthreads();
    }

    // Epilogue. C/D layout: col = lane&15, row = (lane>>4)*4 + reg.
    const int colq = lane & 15;
    const int quad = lane >> 4;
    float bias[4], w3v[4];
#pragma unroll
    for (int j = 0; j < 4; j++) {
        int d = col0 + wn * 64 + j * 16 + colq;
        bias[j] = b1[d * NK + kbr];
        w3v[j] = W3[d];
    }
#pragma unroll
    for (int i = 0; i < 4; i++) {
#pragma unroll
        for (int r = 0; r < 4; r++) {
            float s = 0.f;
#pragma unroll
            for (int j = 0; j < 4; j++) {
                float v = acc[i][j][r] + bias[j];
                s += (v > 0.f) ? v * w3v[j] : 0.f;
            }
            // reduce over the 16 lanes holding the same row
#pragma unroll
            for (int m = 1; m < 16; m <<= 1) s += __shfl_xor(s, m, 64);
            if (colq == 0) {
                int grow = row0 + wm * 64 + i * 16 + quad * 4 + r;
                int b = order[grow];
                if (b >= 0) atomicAdd(out + b, s);
            }
        }
    }
}

// ---------------------------------------------------------------------------
extern "C" void kernel_launch(void* const* d_in, const int* in_sizes, int n_in,
                              void* d_out, int out_size, void* d_ws, size_t ws_size,
                              hipStream_t stream)
{
    const float* x         = (const float*)d_in[0];
    const float* intention = (const float*)d_in[1];
    const float* W1        = (const float*)d_in[2];
    const float* b1        = (const float*)d_in[3];
    const float* W2        = (const float*)d_in[4];
    const float* b2        = (const float*)d_in[5];
    const float* W3        = (const float*)d_in[6];
    const float* b3        = (const float*)d_in[7];
    float* out = (float*)d_out;

    char* ws = (char*)d_ws;
    int*  kidx  = (int*)(ws + OFF_KIDX);
    int*  order = (int*)(ws + OFF_ORDER);
    int*  meta  = (int*)(ws + OFF_META);
    bf16* xg    = (bf16*)(ws + OFF_XG);
    bf16* Wb    = (bf16*)(ws + OFF_WB);

    prep_kernel<<<dim3(1), dim3(256), 0, stream>>>(
        intention, W2, b2, W3, b3, kidx, order, meta, out);
    conv_w1_kernel<<<dim3(NK * ND), dim3(256), 0, stream>>>(W1, Wb);
    gather_x_kernel<<<dim3(MAX_ROWS), dim3(256), 0, stream>>>(x, order, xg);
    gemm_kernel<<<dim3(ND / BN, MAX_TILES), dim3(256), 0, stream>>>(
        xg, Wb, order, meta, b1, W3, out);
}